// Round 7
// baseline (291.436 us; speedup 1.0000x reference)
//
#include <hip/hip_runtime.h>

static constexpr int T_LEN = 512;
static constexpr size_t XG_BYTES = (size_t)2048 * T_LEN * 48 * 4;  // 201 MB

typedef float v2f __attribute__((ext_vector_type(2)));

__device__ __forceinline__ float fsigm(float x) {
    return __builtin_amdgcn_rcpf(1.0f + __expf(-x));
}
__device__ __forceinline__ float ftanh(float x) {
    return 1.0f - 2.0f * __builtin_amdgcn_rcpf(1.0f + __expf(2.0f * x));
}
template <int CTRL>
__device__ __forceinline__ float rotf(float v) {
    return __builtin_bit_cast(float,
        __builtin_amdgcn_mov_dpp(__builtin_bit_cast(int, v), CTRL, 0xf, 0xf, true));
}

// ---------------- Phase A: xg = x @ W_ih0^T + b_ih0  (no seq dependence) ----
// 1 thread per (b,t) row. Weight loads are lane-uniform -> scalar loads.
__global__ __launch_bounds__(256) void xg_gemm(
    const float* __restrict__ x, const float* __restrict__ Wih0,
    const float* __restrict__ bih0, float* __restrict__ xg)
{
    const size_t row = (size_t)blockIdx.x * 256 + threadIdx.x;  // < 2048*512
    const float* xr = x + row * 32;
    float xv[32];
#pragma unroll
    for (int q = 0; q < 8; ++q) {
        float4 v = *(const float4*)(xr + 4 * q);
        xv[4*q+0] = v.x; xv[4*q+1] = v.y; xv[4*q+2] = v.z; xv[4*q+3] = v.w;
    }
    float* og = xg + row * 48;
#pragma unroll
    for (int g4 = 0; g4 < 12; ++g4) {
        float4 o;
        float* po = (float*)&o;
#pragma unroll
        for (int u = 0; u < 4; ++u) {
            const int g = g4 * 4 + u;
            const float* wg = Wih0 + g * 32;
            float acc = bih0[g];
#pragma unroll
            for (int k = 0; k < 32; ++k) acc = fmaf(wg[k], xv[k], acc);
            po[u] = acc;
        }
        *(float4*)(og + 4 * g4) = o;
    }
}

// ---------------- Phase B: recurrent part, xg precomputed ------------------
// Merged-role wave (lanes: j=lane&15, role=(lane>>4)&1, bq=lane>>5), role0 =
// layer-0, role1 = layer-1 one step behind (h0 handoff = 1 shfl_xor/step).
// Per-lane weights now only 96 floats -> pure arch VGPRs (no AGPR churn):
//   WA[g][m]: role0 = (Whh0[row,cm], 0) for r,z ; (0, Whh0[row,cm]) for n
//             role1 = (Wih1[row,cm], Whh1[row,cm]),  cm=(j+m*d1)&15
//   operand pair pA: role0 = (h0, h0) ; role1 = (u, h1)
__global__ __launch_bounds__(256, 1) void gru2_xg(
    const float* __restrict__ xg,
    const float* __restrict__ Whh0, const float* __restrict__ bhh0,
    const float* __restrict__ Wih1, const float* __restrict__ Whh1,
    const float* __restrict__ bih1, const float* __restrict__ bhh1,
    const float* __restrict__ fcw,  const float* __restrict__ fcb,
    float* __restrict__ out)
{
    const int tid  = threadIdx.x;
    const int lane = tid & 63;
    const int j    = lane & 15;
    const int role = (lane >> 4) & 1;
    const int bq   = lane >> 5;
    const int b    = blockIdx.x * 8 + (tid >> 6) * 2 + bq;

    const int d1 = (((int)rotf<0x121>((float)j)) - j) & 15;

    v2f WA[3][16];
    float B_r, B_z, B_in, B_hn;
#pragma unroll
    for (int g = 0; g < 3; ++g) {
        const int row = g * 16 + j;
#pragma unroll
        for (int m = 0; m < 16; ++m) {
            const int cm = (j + m * d1) & 15;
            if (role) {
                WA[g][m].x = Wih1[row * 16 + cm];
                WA[g][m].y = Whh1[row * 16 + cm];
            } else {
                const float w = Whh0[row * 16 + cm];
                WA[g][m].x = (g == 2) ? 0.f : w;   // n-gate dot goes in .y
                WA[g][m].y = (g == 2) ? w : 0.f;   // (multiplied by r)
            }
        }
    }
    if (role) {
        B_r  = bih1[j]      + bhh1[j];
        B_z  = bih1[16 + j] + bhh1[16 + j];
        B_in = bih1[32 + j];
        B_hn = bhh1[32 + j];
    } else {
        B_r  = bhh0[j];
        B_z  = bhh0[16 + j];
        B_in = 0.f;
        B_hn = bhh0[32 + j];
    }
    const float rmask = role ? 0.f : 1.f;   // role1 ignores xg

    float hs = 0.f;   // role0: h0_j ; role1: h1_j

    const float* xgb = xg + (size_t)b * T_LEN * 48;

    // 4-deep xg ring (3 floats/step), named slots (no runtime array indexing)
    float lr0, lz0, ln0, lr1, lz1, ln1, lr2, lz2, ln2, lr3, lz3, ln3;
    lr0 = xgb[0*48 + j]; lz0 = xgb[0*48 + 16 + j]; ln0 = xgb[0*48 + 32 + j];
    lr1 = xgb[1*48 + j]; lz1 = xgb[1*48 + 16 + j]; ln1 = xgb[1*48 + 32 + j];
    lr2 = xgb[2*48 + j]; lz2 = xgb[2*48 + 16 + j]; ln2 = xgb[2*48 + 32 + j];
    lr3 = xgb[3*48 + j]; lz3 = xgb[3*48 + 16 + j]; ln3 = xgb[3*48 + 32 + j];

    auto step = [&](float& Lr, float& Lz, float& Ln, int i) {
        const float us = __shfl_xor(hs, 16, 64);

        const float LXr = Lr * rmask, LXz = Lz * rmask, LXn = Ln * rmask;
        // prefetch row i+4 into the just-freed slot (stays in flight; no
        // barriers anywhere in this kernel)
        const int t4 = (i + 4 < T_LEN) ? (i + 4) : (T_LEN - 1);
        Lr = xgb[t4 * 48 + j];
        Lz = xgb[t4 * 48 + 16 + j];
        Ln = xgb[t4 * 48 + 32 + j];

        v2f pA;
        pA.x = role ? us : hs;
        pA.y = hs;
        v2f aA0 = {0.f, 0.f}, aA1 = {0.f, 0.f}, aA2 = {0.f, 0.f};
#pragma unroll
        for (int m = 0; m < 16; ++m) {
            aA0 = __builtin_elementwise_fma(WA[0][m], pA, aA0);
            aA1 = __builtin_elementwise_fma(WA[1][m], pA, aA1);
            aA2 = __builtin_elementwise_fma(WA[2][m], pA, aA2);
            if (m < 15) { pA.x = rotf<0x121>(pA.x); pA.y = rotf<0x121>(pA.y); }
        }

        const float pre_r = LXr + aA0.x + aA0.y + B_r;
        const float pre_z = LXz + aA1.x + aA1.y + B_z;
        const float xn_p  = LXn + aA2.x + B_in;
        const float hn_p  = aA2.y + B_hn;

        const float r = fsigm(pre_r);
        const float z = fsigm(pre_z);
        const float n = ftanh(xn_p + r * hn_p);
        hs = fmaf(z, hs - n, n);
    };

    // i=0: role0 computes h0[0]; role1 result garbage -> reset
    step(lr0, lz0, ln0, 0);
    hs = role ? 0.f : hs;

    // i = 1..512 (513 total): role0 does t=i (phantom at 512), role1 t=i-1.
#pragma unroll 1
    for (int g = 0; g < 128; ++g) {
        const int i = 1 + 4 * g;
        step(lr1, lz1, ln1, i);
        step(lr2, lz2, ln2, i + 1);
        step(lr3, lz3, ln3, i + 2);
        step(lr0, lz0, ln0, i + 3);
    }

    // FC on final h1 (role1 lanes hold it distributed)
    if (role) {
        float p = fcw[j] * hs;
        p += __shfl_xor(p, 1);
        p += __shfl_xor(p, 2);
        p += __shfl_xor(p, 4);
        p += __shfl_xor(p, 8);
        if (j == 0) out[b] = p + fcb[0];
    }
}

// ---------------- Fallback (R6 kernel): used when ws is too small ----------
__global__ __launch_bounds__(256, 1) void gru2_merged(
    const float* __restrict__ x,
    const float* __restrict__ Wih0, const float* __restrict__ Whh0,
    const float* __restrict__ bih0, const float* __restrict__ bhh0,
    const float* __restrict__ Wih1, const float* __restrict__ Whh1,
    const float* __restrict__ bih1, const float* __restrict__ bhh1,
    const float* __restrict__ fcw,  const float* __restrict__ fcb,
    float* __restrict__ out)
{
    const int tid  = threadIdx.x;
    const int lane = tid & 63;
    const int j    = lane & 15;
    const int role = (lane >> 4) & 1;
    const int bq   = lane >> 5;
    const int b    = blockIdx.x * 8 + (tid >> 6) * 2 + bq;

    const int d1 = (((int)rotf<0x121>((float)j)) - j) & 15;
    const int d2 = (((int)rotf<0x122>((float)j)) - j) & 15;

    v2f WA[3][16];
    v2f WB[3][8];
    float b_r, b_z, b_in, b_hn;
#pragma unroll
    for (int g = 0; g < 3; ++g) {
        const int row = g * 16 + j;
#pragma unroll
        for (int m = 0; m < 16; ++m) {
            const int cm = (j + m * d1) & 15;
            if (role) {
                WA[g][m].x = Wih1[row * 16 + cm];
                WA[g][m].y = Whh1[row * 16 + cm];
            } else {
                WA[g][m].x = Wih0[row * 32 + cm];
                WA[g][m].y = Wih0[row * 32 + 16 + cm];
            }
        }
#pragma unroll
        for (int k = 0; k < 8; ++k) {
            if (role) {
                WB[g][k].x = 0.f; WB[g][k].y = 0.f;
            } else {
                const int e0 = (j + k * d2) & 15;
                const int e1 = (j + d1 + k * d2) & 15;
                WB[g][k].x = Whh0[row * 16 + e0];
                WB[g][k].y = Whh0[row * 16 + e1];
            }
        }
    }
    if (role) {
        b_r  = bih1[j]      + bhh1[j];
        b_z  = bih1[16 + j] + bhh1[16 + j];
        b_in = bih1[32 + j];
        b_hn = bhh1[32 + j];
    } else {
        b_r  = bih0[j]      + bhh0[j];
        b_z  = bih0[16 + j] + bhh0[16 + j];
        b_in = bih0[32 + j];
        b_hn = bhh0[32 + j];
    }

    float hs = 0.f;
    const float* xbase = x + (size_t)b * T_LEN * 32;

    float xl[4], xh[4];
#pragma unroll
    for (int k = 0; k < 4; ++k) {
        xl[k] = xbase[k * 32 + j];
        xh[k] = xbase[k * 32 + 16 + j];
    }

    auto step = [&](int i, int slot) {
        const float us = __shfl_xor(hs, 16, 64);
        const float x0 = xl[slot], x1 = xh[slot];
        const int t4 = (i + 4 < T_LEN) ? (i + 4) : (T_LEN - 1);
        xl[slot] = xbase[t4 * 32 + j];
        xh[slot] = xbase[t4 * 32 + 16 + j];

        v2f pA;
        pA.x = role ? us : x0;
        pA.y = role ? hs : x1;
        v2f pB;
        pB.x = hs;
        pB.y = rotf<0x121>(hs);

        v2f aA0 = {0.f,0.f}, aA1 = {0.f,0.f}, aA2 = {0.f,0.f};
        v2f aB0 = {0.f,0.f}, aB1 = {0.f,0.f}, aB2 = {0.f,0.f};
#pragma unroll
        for (int m = 0; m < 16; ++m) {
            aA0 = __builtin_elementwise_fma(WA[0][m], pA, aA0);
            aA1 = __builtin_elementwise_fma(WA[1][m], pA, aA1);
            aA2 = __builtin_elementwise_fma(WA[2][m], pA, aA2);
            if (m < 8) {
                aB0 = __builtin_elementwise_fma(WB[0][m], pB, aB0);
                aB1 = __builtin_elementwise_fma(WB[1][m], pB, aB1);
                aB2 = __builtin_elementwise_fma(WB[2][m], pB, aB2);
                if (m < 7) { pB.x = rotf<0x122>(pB.x); pB.y = rotf<0x122>(pB.y); }
            }
            if (m < 15) { pA.x = rotf<0x121>(pA.x); pA.y = rotf<0x121>(pA.y); }
        }

        const float pre_r = aA0.x + aA0.y + aB0.x + aB0.y + b_r;
        const float pre_z = aA1.x + aA1.y + aB1.x + aB1.y + b_z;
        const float xn_p = aA2.x + (role ? 0.f : aA2.y);
        const float hn_p = (role ? aA2.y : 0.f) + aB2.x + aB2.y;

        const float r = fsigm(pre_r);
        const float z = fsigm(pre_z);
        const float n = ftanh(xn_p + b_in + r * (hn_p + b_hn));
        hs = fmaf(z, hs - n, n);
    };

    step(0, 0);
    hs = role ? 0.f : hs;
#pragma unroll 1
    for (int i = 1; i <= T_LEN; ++i)
        step(i, i & 3);

    if (role) {
        float p = fcw[j] * hs;
        p += __shfl_xor(p, 1);
        p += __shfl_xor(p, 2);
        p += __shfl_xor(p, 4);
        p += __shfl_xor(p, 8);
        if (j == 0) out[b] = p + fcb[0];
    }
}

extern "C" void kernel_launch(void* const* d_in, const int* in_sizes, int n_in,
                              void* d_out, int out_size, void* d_ws, size_t ws_size,
                              hipStream_t stream) {
    const float* x    = (const float*)d_in[0];
    const float* Wih0 = (const float*)d_in[1];
    const float* Whh0 = (const float*)d_in[2];
    const float* bih0 = (const float*)d_in[3];
    const float* bhh0 = (const float*)d_in[4];
    const float* Wih1 = (const float*)d_in[5];
    const float* Whh1 = (const float*)d_in[6];
    const float* bih1 = (const float*)d_in[7];
    const float* bhh1 = (const float*)d_in[8];
    const float* fcw  = (const float*)d_in[9];
    const float* fcb  = (const float*)d_in[10];

    if (ws_size >= XG_BYTES) {
        float* xg = (float*)d_ws;
        // Phase A: input GEMM for layer 0 (parallel over all b,t)
        xg_gemm<<<(2048 * T_LEN) / 256, 256, 0, stream>>>(x, Wih0, bih0, xg);
        // Phase B: recurrence (stream-ordered after phase A)
        gru2_xg<<<256, 256, 0, stream>>>(xg, Whh0, bhh0, Wih1, Whh1,
                                         bih1, bhh1, fcw, fcb, (float*)d_out);
    } else {
        gru2_merged<<<256, 256, 0, stream>>>(x, Wih0, Whh0, bih0, bhh0,
                                             Wih1, Whh1, bih1, bhh1, fcw, fcb,
                                             (float*)d_out);
    }
}

// Round 8
// 262.030 us; speedup vs baseline: 1.1122x; 1.1122x over previous
//
#include <hip/hip_runtime.h>

static constexpr int T_LEN = 512;
// fp16 xg workspace: [2048][512][48] halves + slack for tail prefetch
static constexpr size_t XG16_BYTES = (size_t)2048 * T_LEN * 48 * 2;
static constexpr size_t WS_NEEDED  = XG16_BYTES + 4096;

typedef float v2f __attribute__((ext_vector_type(2)));

__device__ __forceinline__ float fsigm(float x) {
    return __builtin_amdgcn_rcpf(1.0f + __expf(-x));
}
__device__ __forceinline__ float ftanh(float x) {
    return 1.0f - 2.0f * __builtin_amdgcn_rcpf(1.0f + __expf(2.0f * x));
}
template <int CTRL>
__device__ __forceinline__ float rotf(float v) {
    return __builtin_bit_cast(float,
        __builtin_amdgcn_mov_dpp(__builtin_bit_cast(int, v), CTRL, 0xf, 0xf, true));
}

// ---------------- Phase A: xg = fp16(x @ W_ih0^T + b_ih0) ------------------
// Wave-cooperative: lane (q=lane>>4, j=lane&15); 4 (b,t)-rows per wave-iter.
// Weights live in VGPRs (rotation-permuted); x gathered via DPP row_ror
// systolic chains. 4-deep prefetch ring covers HBM latency. fp16 out halves
// the write+readback traffic (abs err ~1e-3 << 6.2e-3 threshold).
__global__ __launch_bounds__(256) void xg_gemm16(
    const float* __restrict__ x, const float* __restrict__ Wih0,
    const float* __restrict__ bih0, _Float16* __restrict__ xg)
{
    const int tid  = threadIdx.x;
    const int lane = tid & 63;
    const int j    = lane & 15;
    const int q    = lane >> 4;                    // row within 4-row group
    const int wv   = blockIdx.x * 4 + (tid >> 6);  // wave id 0..1023

    const int d1 = (((int)rotf<0x121>((float)j)) - j) & 15;

    v2f W0[16], W1[16], W2[16];
#pragma unroll
    for (int m = 0; m < 16; ++m) {
        const int cm = (j + m * d1) & 15;
        W0[m].x = Wih0[(0*16+j)*32 + cm]; W0[m].y = Wih0[(0*16+j)*32 + 16 + cm];
        W1[m].x = Wih0[(1*16+j)*32 + cm]; W1[m].y = Wih0[(1*16+j)*32 + 16 + cm];
        W2[m].x = Wih0[(2*16+j)*32 + cm]; W2[m].y = Wih0[(2*16+j)*32 + 16 + cm];
    }
    const float b0 = bih0[j], b1 = bih0[16 + j], b2 = bih0[32 + j];

    const size_t row0 = (size_t)wv * 1024 + q;   // rows row0 + 4t, t=0..255
    const float* xl = x  + row0 * 32 + j;        // xl[t*128], xl[t*128+16]
    _Float16*    ob = xg + row0 * 48 + j;        // ob[t*192 + g*16]

    float xa0 = xl[0*128], xb0 = xl[0*128+16];
    float xa1 = xl[1*128], xb1 = xl[1*128+16];
    float xa2 = xl[2*128], xb2 = xl[2*128+16];
    float xa3 = xl[3*128], xb3 = xl[3*128+16];

    auto doRow = [&](float& xa, float& xb, int t) {
        v2f p; p.x = xa; p.y = xb;
        const int t4 = (t + 4 < 256) ? (t + 4) : 255;   // stay in-bounds
        xa = xl[(size_t)t4 * 128];
        xb = xl[(size_t)t4 * 128 + 16];
        v2f a0 = {0.f,0.f}, a1 = {0.f,0.f}, a2 = {0.f,0.f};
#pragma unroll
        for (int m = 0; m < 16; ++m) {
            a0 = __builtin_elementwise_fma(W0[m], p, a0);
            a1 = __builtin_elementwise_fma(W1[m], p, a1);
            a2 = __builtin_elementwise_fma(W2[m], p, a2);
            if (m < 15) { p.x = rotf<0x121>(p.x); p.y = rotf<0x121>(p.y); }
        }
        ob[(size_t)t*192 +  0] = (_Float16)(a0.x + a0.y + b0);
        ob[(size_t)t*192 + 16] = (_Float16)(a1.x + a1.y + b1);
        ob[(size_t)t*192 + 32] = (_Float16)(a2.x + a2.y + b2);
    };
#pragma unroll 1
    for (int t = 0; t < 256; t += 4) {
        doRow(xa0, xb0, t);
        doRow(xa1, xb1, t + 1);
        doRow(xa2, xb2, t + 2);
        doRow(xa3, xb3, t + 3);
    }
}

// ---------------- Phase B: recurrence, K-split for 2 waves/SIMD ------------
// 64 lanes = ONE batch: j=lane&15 (unit), role=bit4 (0:L0, 1:L1 one step
// behind), kh=bit5 (K-half: rotation positions 8kh..8kh+7). 2048 waves ->
// 2/SIMD: two independent recurrence chains per SIMD hide each other's
// shfl/exp/rot stalls. Operand pair p=(h0, hs) serves BOTH roles with no
// selects in the pair (role0: (h0,h0), n-gate weights in .y; role1:
// (h0,h1) = (Wih1,Whh1)). kh-reduce = 4x shfl_xor(32); gate formulas are
// role-uniform. Per-step pk count halved vs R7 (24).
__global__ __launch_bounds__(256, 1) void gru2_kh(
    const _Float16* __restrict__ xg,
    const float* __restrict__ Whh0, const float* __restrict__ bhh0,
    const float* __restrict__ Wih1, const float* __restrict__ Whh1,
    const float* __restrict__ bih1, const float* __restrict__ bhh1,
    const float* __restrict__ fcw,  const float* __restrict__ fcb,
    float* __restrict__ out)
{
    const int tid  = threadIdx.x;
    const int lane = tid & 63;
    const int j    = lane & 15;
    const int role = (lane >> 4) & 1;
    const int kh   = lane >> 5;
    const int b    = blockIdx.x * 4 + (tid >> 6);

    const int d1 = (((int)rotf<0x121>((float)j)) - j) & 15;

    // Wp[g][mp]: .x multiplies p.x(=h0), .y multiplies p.y(=hs-partner-h)
    v2f Wp[3][8];
    float B_r, B_z, B_in, B_hn, rmask;
#pragma unroll
    for (int g = 0; g < 3; ++g) {
        const int row = g * 16 + j;
#pragma unroll
        for (int mp = 0; mp < 8; ++mp) {
            const int cm = (j + (8 * kh + mp) * d1) & 15;
            if (role) {
                Wp[g][mp].x = Wih1[row * 16 + cm];
                Wp[g][mp].y = Whh1[row * 16 + cm];
            } else {
                const float w = Whh0[row * 16 + cm];
                Wp[g][mp].x = (g == 2) ? 0.f : w;   // n-dot goes through .y
                Wp[g][mp].y = (g == 2) ? w : 0.f;   // (multiplied by r later)
            }
        }
    }
    if (role) {
        B_r = bih1[j] + bhh1[j];  B_z = bih1[16 + j] + bhh1[16 + j];
        B_in = bih1[32 + j];      B_hn = bhh1[32 + j];  rmask = 0.f;
    } else {
        B_r = bhh0[j];  B_z = bhh0[16 + j];
        B_in = 0.f;     B_hn = bhh0[32 + j];            rmask = 1.f;
    }

    float hs = 0.f;   // role0: h0_j ; role1: h1_j (kh copies identical)

    const _Float16* xgb = xg + (size_t)b * T_LEN * 48 + j;

    // 4-deep xg ring, named slots
    float lr0,lz0,ln0, lr1,lz1,ln1, lr2,lz2,ln2, lr3,lz3,ln3;
    lr0=(float)xgb[0*48]; lz0=(float)xgb[0*48+16]; ln0=(float)xgb[0*48+32];
    lr1=(float)xgb[1*48]; lz1=(float)xgb[1*48+16]; ln1=(float)xgb[1*48+32];
    lr2=(float)xgb[2*48]; lz2=(float)xgb[2*48+16]; ln2=(float)xgb[2*48+32];
    lr3=(float)xgb[3*48]; lz3=(float)xgb[3*48+16]; ln3=(float)xgb[3*48+32];

    auto step = [&](float& Lr, float& Lz, float& Ln, int i) {
        const float us = __shfl_xor(hs, 16, 64);   // exchange h across roles
        const float Xr = Lr * rmask, Xz = Lz * rmask, Xn = Ln * rmask;
        // prefetch i+4 (clamped to written region -> no uninitialized reads)
        int t4 = i + 4; if (t4 > T_LEN - 1) t4 = T_LEN - 1;
        Lr = (float)xgb[t4*48]; Lz = (float)xgb[t4*48+16]; Ln = (float)xgb[t4*48+32];

        float A = role ? us : hs;        // h0 in ALL lanes
        // kh=1 lanes start 8 positions ahead
        const float A8 = rotf<0x128>(A);
        const float H8 = rotf<0x128>(hs);
        v2f p;
        p.x = kh ? A8 : A;
        p.y = kh ? H8 : hs;
        v2f a0 = {0.f,0.f}, a1 = {0.f,0.f}, a2 = {0.f,0.f};
#pragma unroll
        for (int mp = 0; mp < 8; ++mp) {
            a0 = __builtin_elementwise_fma(Wp[0][mp], p, a0);
            a1 = __builtin_elementwise_fma(Wp[1][mp], p, a1);
            a2 = __builtin_elementwise_fma(Wp[2][mp], p, a2);
            if (mp < 7) { p.x = rotf<0x121>(p.x); p.y = rotf<0x121>(p.y); }
        }
        // kh-reduction (lane ^ 32); role-uniform gate math afterwards
        float v0 = a0.x + a0.y;
        float v1 = a1.x + a1.y;
        float v2x = a2.x, v2y = a2.y;
        v0  += __shfl_xor(v0, 32, 64);
        v1  += __shfl_xor(v1, 32, 64);
        v2x += __shfl_xor(v2x, 32, 64);
        v2y += __shfl_xor(v2y, 32, 64);
        const float r = fsigm(Xr + v0 + B_r);
        const float z = fsigm(Xz + v1 + B_z);
        const float n = ftanh(Xn + v2x + B_in + r * (v2y + B_hn));
        hs = fmaf(z, hs - n, n);
    };

    // i=0: role0 computes h0[0]; role1 result garbage -> reset
    step(lr0, lz0, ln0, 0);
    hs = role ? 0.f : hs;

    // i=1..512: role0 does t=i (phantom at 512, harmless); role1 does t=i-1
#pragma unroll 1
    for (int g = 0; g < 128; ++g) {
        const int i = 1 + 4 * g;
        step(lr1, lz1, ln1, i);
        step(lr2, lz2, ln2, i + 1);
        step(lr3, lz3, ln3, i + 2);
        step(lr0, lz0, ln0, i + 3);
    }

    // FC on final h1 (role1 lanes, kh=0 writes)
    if (role) {
        float pfc = fcw[j] * hs;
        pfc += __shfl_xor(pfc, 1, 64);
        pfc += __shfl_xor(pfc, 2, 64);
        pfc += __shfl_xor(pfc, 4, 64);
        pfc += __shfl_xor(pfc, 8, 64);
        if (j == 0 && kh == 0) out[b] = pfc + fcb[0];
    }
}

// ---------------- Fallback (R6 kernel): used when ws is too small ----------
__global__ __launch_bounds__(256, 1) void gru2_merged(
    const float* __restrict__ x,
    const float* __restrict__ Wih0, const float* __restrict__ Whh0,
    const float* __restrict__ bih0, const float* __restrict__ bhh0,
    const float* __restrict__ Wih1, const float* __restrict__ Whh1,
    const float* __restrict__ bih1, const float* __restrict__ bhh1,
    const float* __restrict__ fcw,  const float* __restrict__ fcb,
    float* __restrict__ out)
{
    const int tid  = threadIdx.x;
    const int lane = tid & 63;
    const int j    = lane & 15;
    const int role = (lane >> 4) & 1;
    const int bq   = lane >> 5;
    const int b    = blockIdx.x * 8 + (tid >> 6) * 2 + bq;

    const int d1 = (((int)rotf<0x121>((float)j)) - j) & 15;
    const int d2 = (((int)rotf<0x122>((float)j)) - j) & 15;

    v2f WA[3][16];
    v2f WB[3][8];
    float b_r, b_z, b_in, b_hn;
#pragma unroll
    for (int g = 0; g < 3; ++g) {
        const int row = g * 16 + j;
#pragma unroll
        for (int m = 0; m < 16; ++m) {
            const int cm = (j + m * d1) & 15;
            if (role) {
                WA[g][m].x = Wih1[row * 16 + cm];
                WA[g][m].y = Whh1[row * 16 + cm];
            } else {
                WA[g][m].x = Wih0[row * 32 + cm];
                WA[g][m].y = Wih0[row * 32 + 16 + cm];
            }
        }
#pragma unroll
        for (int k = 0; k < 8; ++k) {
            if (role) {
                WB[g][k].x = 0.f; WB[g][k].y = 0.f;
            } else {
                const int e0 = (j + k * d2) & 15;
                const int e1 = (j + d1 + k * d2) & 15;
                WB[g][k].x = Whh0[row * 16 + e0];
                WB[g][k].y = Whh0[row * 16 + e1];
            }
        }
    }
    if (role) {
        b_r  = bih1[j]      + bhh1[j];
        b_z  = bih1[16 + j] + bhh1[16 + j];
        b_in = bih1[32 + j];
        b_hn = bhh1[32 + j];
    } else {
        b_r  = bih0[j]      + bhh0[j];
        b_z  = bih0[16 + j] + bhh0[16 + j];
        b_in = bih0[32 + j];
        b_hn = bhh0[32 + j];
    }

    float hs = 0.f;
    const float* xbase = x + (size_t)b * T_LEN * 32;

    float xl[4], xh[4];
#pragma unroll
    for (int k = 0; k < 4; ++k) {
        xl[k] = xbase[k * 32 + j];
        xh[k] = xbase[k * 32 + 16 + j];
    }

    auto step = [&](int i, int slot) {
        const float us = __shfl_xor(hs, 16, 64);
        const float x0 = xl[slot], x1 = xh[slot];
        const int t4 = (i + 4 < T_LEN) ? (i + 4) : (T_LEN - 1);
        xl[slot] = xbase[t4 * 32 + j];
        xh[slot] = xbase[t4 * 32 + 16 + j];

        v2f pA;
        pA.x = role ? us : x0;
        pA.y = role ? hs : x1;
        v2f pB;
        pB.x = hs;
        pB.y = rotf<0x121>(hs);

        v2f aA0 = {0.f,0.f}, aA1 = {0.f,0.f}, aA2 = {0.f,0.f};
        v2f aB0 = {0.f,0.f}, aB1 = {0.f,0.f}, aB2 = {0.f,0.f};
#pragma unroll
        for (int m = 0; m < 16; ++m) {
            aA0 = __builtin_elementwise_fma(WA[0][m], pA, aA0);
            aA1 = __builtin_elementwise_fma(WA[1][m], pA, aA1);
            aA2 = __builtin_elementwise_fma(WA[2][m], pA, aA2);
            if (m < 8) {
                aB0 = __builtin_elementwise_fma(WB[0][m], pB, aB0);
                aB1 = __builtin_elementwise_fma(WB[1][m], pB, aB1);
                aB2 = __builtin_elementwise_fma(WB[2][m], pB, aB2);
                if (m < 7) { pB.x = rotf<0x122>(pB.x); pB.y = rotf<0x122>(pB.y); }
            }
            if (m < 15) { pA.x = rotf<0x121>(pA.x); pA.y = rotf<0x121>(pA.y); }
        }

        const float pre_r = aA0.x + aA0.y + aB0.x + aB0.y + b_r;
        const float pre_z = aA1.x + aA1.y + aB1.x + aB1.y + b_z;
        const float xn_p = aA2.x + (role ? 0.f : aA2.y);
        const float hn_p = (role ? aA2.y : 0.f) + aB2.x + aB2.y;

        const float r = fsigm(pre_r);
        const float z = fsigm(pre_z);
        const float n = ftanh(xn_p + b_in + r * (hn_p + b_hn));
        hs = fmaf(z, hs - n, n);
    };

    step(0, 0);
    hs = role ? 0.f : hs;
#pragma unroll 1
    for (int i = 1; i <= T_LEN; ++i)
        step(i, i & 3);

    if (role) {
        float p = fcw[j] * hs;
        p += __shfl_xor(p, 1);
        p += __shfl_xor(p, 2);
        p += __shfl_xor(p, 4);
        p += __shfl_xor(p, 8);
        if (j == 0) out[b] = p + fcb[0];
    }
}

extern "C" void kernel_launch(void* const* d_in, const int* in_sizes, int n_in,
                              void* d_out, int out_size, void* d_ws, size_t ws_size,
                              hipStream_t stream) {
    const float* x    = (const float*)d_in[0];
    const float* Wih0 = (const float*)d_in[1];
    const float* Whh0 = (const float*)d_in[2];
    const float* bih0 = (const float*)d_in[3];
    const float* bhh0 = (const float*)d_in[4];
    const float* Wih1 = (const float*)d_in[5];
    const float* Whh1 = (const float*)d_in[6];
    const float* bih1 = (const float*)d_in[7];
    const float* bhh1 = (const float*)d_in[8];
    const float* fcw  = (const float*)d_in[9];
    const float* fcb  = (const float*)d_in[10];

    if (ws_size >= WS_NEEDED) {
        _Float16* xg16 = (_Float16*)d_ws;
        // Phase A: input GEMM for layer 0 (1024 waves, DPP-dot, fp16 out)
        xg_gemm16<<<256, 256, 0, stream>>>(x, Wih0, bih0, xg16);
        // Phase B: recurrence, 64 lanes/batch -> 2048 waves = 2/SIMD
        gru2_kh<<<512, 256, 0, stream>>>(xg16, Whh0, bhh0, Wih1, Whh1,
                                         bih1, bhh1, fcw, fcb, (float*)d_out);
    } else {
        gru2_merged<<<256, 256, 0, stream>>>(x, Wih0, Whh0, bih0, bhh0,
                                             Wih1, Whh1, bih1, bhh1, fcw, fcb,
                                             (float*)d_out);
    }
}

// Round 9
// 222.999 us; speedup vs baseline: 1.3069x; 1.1750x over previous
//
#include <hip/hip_runtime.h>

static constexpr int T_LEN = 512;
// fp16 xg workspace: [2048][512][48] halves
static constexpr size_t XG16_BYTES = (size_t)2048 * T_LEN * 48 * 2;
static constexpr size_t WS_NEEDED  = XG16_BYTES + 4096;

typedef float v2f __attribute__((ext_vector_type(2)));

__device__ __forceinline__ float fsigm(float x) {
    return __builtin_amdgcn_rcpf(1.0f + __expf(-x));
}
__device__ __forceinline__ float ftanh(float x) {
    return 1.0f - 2.0f * __builtin_amdgcn_rcpf(1.0f + __expf(2.0f * x));
}
template <int CTRL>
__device__ __forceinline__ float rotf(float v) {
    return __builtin_bit_cast(float,
        __builtin_amdgcn_mov_dpp(__builtin_bit_cast(int, v), CTRL, 0xf, 0xf, true));
}
// GUARANTEED packed fp32 FMA: acc = a*b + acc as ONE v_pk_fma_f32.
// Tied "+v" accumulator -> no copies; non-volatile asm stays schedulable.
__device__ __forceinline__ void pk_acc(v2f& acc, v2f a, v2f b) {
    asm("v_pk_fma_f32 %0, %1, %2, %0" : "+v"(acc) : "v"(a), "v"(b));
}

// ---------------- Phase A: xg = fp16(x @ W_ih0^T + b_ih0) ------------------
__global__ __launch_bounds__(256) void xg_gemm16(
    const float* __restrict__ x, const float* __restrict__ Wih0,
    const float* __restrict__ bih0, _Float16* __restrict__ xg)
{
    const int tid  = threadIdx.x;
    const int lane = tid & 63;
    const int j    = lane & 15;
    const int q    = lane >> 4;                    // row within 4-row group
    const int wv   = blockIdx.x * 4 + (tid >> 6);  // wave id 0..1023

    const int d1 = (((int)rotf<0x121>((float)j)) - j) & 15;

    v2f W0[16], W1[16], W2[16];
#pragma unroll
    for (int m = 0; m < 16; ++m) {
        const int cm = (j + m * d1) & 15;
        W0[m].x = Wih0[(0*16+j)*32 + cm]; W0[m].y = Wih0[(0*16+j)*32 + 16 + cm];
        W1[m].x = Wih0[(1*16+j)*32 + cm]; W1[m].y = Wih0[(1*16+j)*32 + 16 + cm];
        W2[m].x = Wih0[(2*16+j)*32 + cm]; W2[m].y = Wih0[(2*16+j)*32 + 16 + cm];
    }
    const float b0 = bih0[j], b1 = bih0[16 + j], b2 = bih0[32 + j];

    const size_t row0 = (size_t)wv * 1024 + q;   // rows row0 + 4t, t=0..255
    const float* xl = x  + row0 * 32 + j;
    _Float16*    ob = xg + row0 * 48 + j;

    float xa0 = xl[0*128], xb0 = xl[0*128+16];
    float xa1 = xl[1*128], xb1 = xl[1*128+16];
    float xa2 = xl[2*128], xb2 = xl[2*128+16];
    float xa3 = xl[3*128], xb3 = xl[3*128+16];

    auto doRow = [&](float& xa, float& xb, int t) {
        v2f p; p.x = xa; p.y = xb;
        const int t4 = (t + 4 < 256) ? (t + 4) : 255;
        xa = xl[(size_t)t4 * 128];
        xb = xl[(size_t)t4 * 128 + 16];
        v2f a0 = {0.f,0.f}, a1 = {0.f,0.f}, a2 = {0.f,0.f};
#pragma unroll
        for (int m = 0; m < 16; ++m) {
            pk_acc(a0, W0[m], p);
            pk_acc(a1, W1[m], p);
            pk_acc(a2, W2[m], p);
            if (m < 15) { p.x = rotf<0x121>(p.x); p.y = rotf<0x121>(p.y); }
        }
        ob[(size_t)t*192 +  0] = (_Float16)(a0.x + a0.y + b0);
        ob[(size_t)t*192 + 16] = (_Float16)(a1.x + a1.y + b1);
        ob[(size_t)t*192 + 32] = (_Float16)(a2.x + a2.y + b2);
    };
#pragma unroll 1
    for (int t = 0; t < 256; t += 4) {
        doRow(xa0, xb0, t);
        doRow(xa1, xb1, t + 1);
        doRow(xa2, xb2, t + 2);
        doRow(xa3, xb3, t + 3);
    }
}

// ---------------- Phase B: recurrence (R7 32-lane layout + asm pk_fma) -----
// Lanes: j=lane&15 (unit), role=bit4 (0:L0, 1:L1 one step behind), bq=bit5
// (batch). 1024 waves, 1/SIMD. ONE shuffle per step (h0 handoff), no
// reductions. Dot = DPP row_ror systolic, 48 v_pk_fma_f32 (inline asm,
// tied accumulator) per step covering both layers of 2 batches.
//   WA[g][m]: role0 = (Whh0[row,cm],0) for r,z ; (0,Whh0[row,cm]) for n
//             role1 = (Wih1[row,cm], Whh1[row,cm]),  cm=(j+m*d1)&15
//   p = (role? us : hs, hs)
__global__ __launch_bounds__(256, 1) void gru2_pk(
    const _Float16* __restrict__ xg,
    const float* __restrict__ Whh0, const float* __restrict__ bhh0,
    const float* __restrict__ Wih1, const float* __restrict__ Whh1,
    const float* __restrict__ bih1, const float* __restrict__ bhh1,
    const float* __restrict__ fcw,  const float* __restrict__ fcb,
    float* __restrict__ out)
{
    const int tid  = threadIdx.x;
    const int lane = tid & 63;
    const int j    = lane & 15;
    const int role = (lane >> 4) & 1;
    const int bq   = lane >> 5;
    const int b    = blockIdx.x * 8 + (tid >> 6) * 2 + bq;

    const int d1 = (((int)rotf<0x121>((float)j)) - j) & 15;

    v2f WA[3][16];
    float B_r, B_z, B_in, B_hn, rmask;
#pragma unroll
    for (int g = 0; g < 3; ++g) {
        const int row = g * 16 + j;
#pragma unroll
        for (int m = 0; m < 16; ++m) {
            const int cm = (j + m * d1) & 15;
            if (role) {
                WA[g][m].x = Wih1[row * 16 + cm];
                WA[g][m].y = Whh1[row * 16 + cm];
            } else {
                const float w = Whh0[row * 16 + cm];
                WA[g][m].x = (g == 2) ? 0.f : w;
                WA[g][m].y = (g == 2) ? w : 0.f;
            }
        }
    }
    if (role) {
        B_r = bih1[j] + bhh1[j];  B_z = bih1[16 + j] + bhh1[16 + j];
        B_in = bih1[32 + j];      B_hn = bhh1[32 + j];  rmask = 0.f;
    } else {
        B_r = bhh0[j];  B_z = bhh0[16 + j];
        B_in = 0.f;     B_hn = bhh0[32 + j];            rmask = 1.f;
    }

    float hs = 0.f;   // role0: h0_j ; role1: h1_j

    const _Float16* xgb = xg + (size_t)b * T_LEN * 48 + j;

    // 4-deep xg ring, named slots
    float lr0,lz0,ln0, lr1,lz1,ln1, lr2,lz2,ln2, lr3,lz3,ln3;
    lr0=(float)xgb[0*48]; lz0=(float)xgb[0*48+16]; ln0=(float)xgb[0*48+32];
    lr1=(float)xgb[1*48]; lz1=(float)xgb[1*48+16]; ln1=(float)xgb[1*48+32];
    lr2=(float)xgb[2*48]; lz2=(float)xgb[2*48+16]; ln2=(float)xgb[2*48+32];
    lr3=(float)xgb[3*48]; lz3=(float)xgb[3*48+16]; ln3=(float)xgb[3*48+32];

    auto step = [&](float& Lr, float& Lz, float& Ln, int i) {
        // issue the role handoff first; its ~50cy latency is covered by the
        // independent loads/cvts/muls below.
        const float us = __shfl_xor(hs, 16, 64);

        const float Xr = Lr * rmask, Xz = Lz * rmask, Xn = Ln * rmask;
        int t4 = i + 4; if (t4 > T_LEN - 1) t4 = T_LEN - 1;   // stay in valid xg
        Lr = (float)xgb[t4*48]; Lz = (float)xgb[t4*48+16]; Ln = (float)xgb[t4*48+32];

        v2f p;
        p.x = role ? us : hs;
        p.y = hs;
        v2f a0 = {0.f,0.f}, a1 = {0.f,0.f}, a2 = {0.f,0.f};
#pragma unroll
        for (int m = 0; m < 16; ++m) {
            pk_acc(a0, WA[0][m], p);
            pk_acc(a1, WA[1][m], p);
            pk_acc(a2, WA[2][m], p);
            if (m < 15) { p.x = rotf<0x121>(p.x); p.y = rotf<0x121>(p.y); }
        }

        const float r = fsigm(Xr + a0.x + a0.y + B_r);
        const float z = fsigm(Xz + a1.x + a1.y + B_z);
        const float n = ftanh(Xn + a2.x + B_in + r * (a2.y + B_hn));
        hs = fmaf(z, hs - n, n);
    };

    // i=0: role0 computes h0[0]; role1 result garbage -> reset
    step(lr0, lz0, ln0, 0);
    hs = role ? 0.f : hs;

    // i=1..512: role0 does t=i (phantom at 512, harmless); role1 does t=i-1
#pragma unroll 1
    for (int g = 0; g < 128; ++g) {
        const int i = 1 + 4 * g;
        step(lr1, lz1, ln1, i);
        step(lr2, lz2, ln2, i + 1);
        step(lr3, lz3, ln3, i + 2);
        step(lr0, lz0, ln0, i + 3);
    }

    // FC on final h1 (role1 lanes hold it distributed)
    if (role) {
        float pfc = fcw[j] * hs;
        pfc += __shfl_xor(pfc, 1, 64);
        pfc += __shfl_xor(pfc, 2, 64);
        pfc += __shfl_xor(pfc, 4, 64);
        pfc += __shfl_xor(pfc, 8, 64);
        if (j == 0) out[b] = pfc + fcb[0];
    }
}

// ---------------- Fallback (R6 kernel): used when ws is too small ----------
__global__ __launch_bounds__(256, 1) void gru2_merged(
    const float* __restrict__ x,
    const float* __restrict__ Wih0, const float* __restrict__ Whh0,
    const float* __restrict__ bih0, const float* __restrict__ bhh0,
    const float* __restrict__ Wih1, const float* __restrict__ Whh1,
    const float* __restrict__ bih1, const float* __restrict__ bhh1,
    const float* __restrict__ fcw,  const float* __restrict__ fcb,
    float* __restrict__ out)
{
    const int tid  = threadIdx.x;
    const int lane = tid & 63;
    const int j    = lane & 15;
    const int role = (lane >> 4) & 1;
    const int bq   = lane >> 5;
    const int b    = blockIdx.x * 8 + (tid >> 6) * 2 + bq;

    const int d1 = (((int)rotf<0x121>((float)j)) - j) & 15;
    const int d2 = (((int)rotf<0x122>((float)j)) - j) & 15;

    v2f WA[3][16];
    v2f WB[3][8];
    float b_r, b_z, b_in, b_hn;
#pragma unroll
    for (int g = 0; g < 3; ++g) {
        const int row = g * 16 + j;
#pragma unroll
        for (int m = 0; m < 16; ++m) {
            const int cm = (j + m * d1) & 15;
            if (role) {
                WA[g][m].x = Wih1[row * 16 + cm];
                WA[g][m].y = Whh1[row * 16 + cm];
            } else {
                WA[g][m].x = Wih0[row * 32 + cm];
                WA[g][m].y = Wih0[row * 32 + 16 + cm];
            }
        }
#pragma unroll
        for (int k = 0; k < 8; ++k) {
            if (role) {
                WB[g][k].x = 0.f; WB[g][k].y = 0.f;
            } else {
                const int e0 = (j + k * d2) & 15;
                const int e1 = (j + d1 + k * d2) & 15;
                WB[g][k].x = Whh0[row * 16 + e0];
                WB[g][k].y = Whh0[row * 16 + e1];
            }
        }
    }
    if (role) {
        b_r  = bih1[j]      + bhh1[j];
        b_z  = bih1[16 + j] + bhh1[16 + j];
        b_in = bih1[32 + j];
        b_hn = bhh1[32 + j];
    } else {
        b_r  = bih0[j]      + bhh0[j];
        b_z  = bih0[16 + j] + bhh0[16 + j];
        b_in = bih0[32 + j];
        b_hn = bhh0[32 + j];
    }

    float hs = 0.f;
    const float* xbase = x + (size_t)b * T_LEN * 32;

    float xl[4], xh[4];
#pragma unroll
    for (int k = 0; k < 4; ++k) {
        xl[k] = xbase[k * 32 + j];
        xh[k] = xbase[k * 32 + 16 + j];
    }

    auto step = [&](int i, int slot) {
        const float us = __shfl_xor(hs, 16, 64);
        const float x0 = xl[slot], x1 = xh[slot];
        const int t4 = (i + 4 < T_LEN) ? (i + 4) : (T_LEN - 1);
        xl[slot] = xbase[t4 * 32 + j];
        xh[slot] = xbase[t4 * 32 + 16 + j];

        v2f pA;
        pA.x = role ? us : x0;
        pA.y = role ? hs : x1;
        v2f pB;
        pB.x = hs;
        pB.y = rotf<0x121>(hs);

        v2f aA0 = {0.f,0.f}, aA1 = {0.f,0.f}, aA2 = {0.f,0.f};
        v2f aB0 = {0.f,0.f}, aB1 = {0.f,0.f}, aB2 = {0.f,0.f};
#pragma unroll
        for (int m = 0; m < 16; ++m) {
            pk_acc(aA0, WA[0][m], pA);
            pk_acc(aA1, WA[1][m], pA);
            pk_acc(aA2, WA[2][m], pA);
            if (m < 8) {
                pk_acc(aB0, WB[0][m], pB);
                pk_acc(aB1, WB[1][m], pB);
                pk_acc(aB2, WB[2][m], pB);
                if (m < 7) { pB.x = rotf<0x122>(pB.x); pB.y = rotf<0x122>(pB.y); }
            }
            if (m < 15) { pA.x = rotf<0x121>(pA.x); pA.y = rotf<0x121>(pA.y); }
        }

        const float pre_r = aA0.x + aA0.y + aB0.x + aB0.y + b_r;
        const float pre_z = aA1.x + aA1.y + aB1.x + aB1.y + b_z;
        const float xn_p = aA2.x + (role ? 0.f : aA2.y);
        const float hn_p = (role ? aA2.y : 0.f) + aB2.x + aB2.y;

        const float r = fsigm(pre_r);
        const float z = fsigm(pre_z);
        const float n = ftanh(xn_p + b_in + r * (hn_p + b_hn));
        hs = fmaf(z, hs - n, n);
    };

    step(0, 0);
    hs = role ? 0.f : hs;
#pragma unroll 1
    for (int i = 1; i <= T_LEN; ++i)
        step(i, i & 3);

    if (role) {
        float p = fcw[j] * hs;
        p += __shfl_xor(p, 1);
        p += __shfl_xor(p, 2);
        p += __shfl_xor(p, 4);
        p += __shfl_xor(p, 8);
        if (j == 0) out[b] = p + fcb[0];
    }
}

extern "C" void kernel_launch(void* const* d_in, const int* in_sizes, int n_in,
                              void* d_out, int out_size, void* d_ws, size_t ws_size,
                              hipStream_t stream) {
    const float* x    = (const float*)d_in[0];
    const float* Wih0 = (const float*)d_in[1];
    const float* Whh0 = (const float*)d_in[2];
    const float* bih0 = (const float*)d_in[3];
    const float* bhh0 = (const float*)d_in[4];
    const float* Wih1 = (const float*)d_in[5];
    const float* Whh1 = (const float*)d_in[6];
    const float* bih1 = (const float*)d_in[7];
    const float* bhh1 = (const float*)d_in[8];
    const float* fcw  = (const float*)d_in[9];
    const float* fcb  = (const float*)d_in[10];

    if (ws_size >= WS_NEEDED) {
        _Float16* xg16 = (_Float16*)d_ws;
        // Phase A: input GEMM for layer 0 (1024 waves, DPP-dot, fp16 out)
        xg_gemm16<<<256, 256, 0, stream>>>(x, Wih0, bih0, xg16);
        // Phase B: recurrence, 32 lanes/batch (j x role), 1024 waves
        gru2_pk<<<256, 256, 0, stream>>>(xg16, Whh0, bhh0, Wih1, Whh1,
                                         bih1, bhh1, fcw, fcb, (float*)d_out);
    } else {
        gru2_merged<<<256, 256, 0, stream>>>(x, Wih0, Whh0, bih0, bhh0,
                                             Wih1, Whh1, bih1, bhh1, fcw, fcb,
                                             (float*)d_out);
    }
}